// Round 3
// baseline (589.500 us; speedup 1.0000x reference)
//
#include <hip/hip_runtime.h>
#include <math.h>

#define B_ 64
#define QL_ 32
#define DL_ 2048
#define E_ 768
#define NBINS_ 30
#define NT 256
#define KT 64

// ws layout:
//   invq : [0,      8192)        2048 f32
//   gate : [8192,   16384)       2048 f32
//   hist : [16384,  262144)      64*32*30 u32

__global__ __launch_bounds__(256) void qprep_kernel(const float* __restrict__ query,
                                                    const float* __restrict__ wg,
                                                    const float* __restrict__ bgp,
                                                    float* __restrict__ invq,
                                                    float* __restrict__ gate) {
  const int row = blockIdx.x * 4 + (threadIdx.x >> 6);
  const int l = threadIdx.x & 63;
  const float* qp = query + (size_t)row * E_;
  float ss = 0.f, dg = 0.f;
#pragma unroll
  for (int c = 0; c < 3; ++c) {
    float4 q4 = *reinterpret_cast<const float4*>(qp + (size_t)(l + c * 64) * 4);
    float4 w4 = *reinterpret_cast<const float4*>(wg + (size_t)(l + c * 64) * 4);
    ss += q4.x * q4.x + q4.y * q4.y + q4.z * q4.z + q4.w * q4.w;
    dg += q4.x * w4.x + q4.y * w4.y + q4.z * w4.z + q4.w * w4.w;
  }
#pragma unroll
  for (int m = 1; m < 64; m <<= 1) {
    ss += __shfl_xor(ss, m, 64);
    dg += __shfl_xor(dg, m, 64);
  }
  if (l == 0) {
    invq[row] = rsqrtf(ss);
    gate[row] = dg + bgp[0];
  }
}

__global__ __launch_bounds__(256) void interaction_kernel(const float* __restrict__ query,
                                                          const float* __restrict__ doc,
                                                          const float* __restrict__ invq,
                                                          unsigned int* __restrict__ hist) {
  __shared__ float As[KT][36];       // A transposed [k][q], pad 36: conflict-free writes, broadcast reads
  __shared__ float Bs[KT][260];      // B transposed [k][n'], n' = n ^ (4*((k>>3)&7)) 16B-XOR swizzle
  __shared__ float invd_s[NT];
  __shared__ float invq_s[QL_];

  const int tid = threadIdx.x;
  const int b = blockIdx.y;
  const int n0 = blockIdx.x * NT;
  const int rg = tid >> 5;      // 0..7  (q group: q = rg*4 + i)
  const int cg = tid & 31;      // 0..31 (n group: n = cg*4+j / 128+cg*4+j)
  const int kq = tid & 15;      // B staging: which float4 along k
  const int rr = tid >> 4;      // 0..15 (B staging row within pass)
  const int qa = tid & 31;      // A staging: q row
  const int pc = tid >> 5;      // A staging: k piece (8 floats)

  if (tid < QL_) invq_s[tid] = invq[b * QL_ + tid];

  float acc[4][8];
#pragma unroll
  for (int i = 0; i < 4; ++i)
#pragma unroll
    for (int j = 0; j < 8; ++j) acc[i][j] = 0.f;
  float sq[16];
#pragma unroll
  for (int p = 0; p < 16; ++p) sq[p] = 0.f;

  const float* qbase = query + (size_t)b * QL_ * E_;
  const float* dbase = doc + (size_t)(b * DL_ + n0) * E_;

  // write-side swizzle: rows written are 4*kq+c, (row>>3)&7 == kq>>1 for all c in 0..3
  const int xw = 4 * (kq >> 1);

  for (int ch = 0; ch < E_ / KT; ++ch) {
    const int k0 = ch * KT;
    __syncthreads();
    // --- stage A (32q x 64k), transposed ---
    {
      const float* gp = qbase + (size_t)qa * E_ + k0 + pc * 8;
      float4 a0 = *reinterpret_cast<const float4*>(gp);
      float4 a1 = *reinterpret_cast<const float4*>(gp + 4);
      As[pc * 8 + 0][qa] = a0.x; As[pc * 8 + 1][qa] = a0.y;
      As[pc * 8 + 2][qa] = a0.z; As[pc * 8 + 3][qa] = a0.w;
      As[pc * 8 + 4][qa] = a1.x; As[pc * 8 + 5][qa] = a1.y;
      As[pc * 8 + 6][qa] = a1.z; As[pc * 8 + 7][qa] = a1.w;
    }
    // --- stage B (256n x 64k), transposed + XOR-swizzled, + doc sumsq on the fly ---
#pragma unroll
    for (int p = 0; p < 16; ++p) {
      const int r = p * 16 + rr;
      const int rs = r ^ xw;
      float4 v = *reinterpret_cast<const float4*>(dbase + (size_t)r * E_ + k0 + kq * 4);
      sq[p] += v.x * v.x + v.y * v.y + v.z * v.z + v.w * v.w;
      Bs[kq * 4 + 0][rs] = v.x; Bs[kq * 4 + 1][rs] = v.y;
      Bs[kq * 4 + 2][rs] = v.z; Bs[kq * 4 + 3][rs] = v.w;
    }
    if (ch == E_ / KT - 1) {
      // finish doc row norms: reduce across the 16 lanes sharing each row
#pragma unroll
      for (int p = 0; p < 16; ++p) {
        float s = sq[p];
        s += __shfl_xor(s, 1, 64);
        s += __shfl_xor(s, 2, 64);
        s += __shfl_xor(s, 4, 64);
        s += __shfl_xor(s, 8, 64);
        if ((tid & 15) == 0) invd_s[p * 16 + rr] = rsqrtf(s);
      }
    }
    __syncthreads();
    // --- GEMM over this k-chunk ---
#pragma unroll 8
    for (int k = 0; k < KT; ++k) {
      const int xk = 4 * ((k >> 3) & 7);
      float4 a = *reinterpret_cast<const float4*>(&As[k][rg * 4]);
      float4 b0 = *reinterpret_cast<const float4*>(&Bs[k][(cg * 4) ^ xk]);
      float4 b1 = *reinterpret_cast<const float4*>(&Bs[k][128 + ((cg * 4) ^ xk)]);
      const float av[4] = {a.x, a.y, a.z, a.w};
      const float bv[8] = {b0.x, b0.y, b0.z, b0.w, b1.x, b1.y, b1.z, b1.w};
#pragma unroll
      for (int i = 0; i < 4; ++i)
#pragma unroll
        for (int j = 0; j < 8; ++j) acc[i][j] = fmaf(av[i], bv[j], acc[i][j]);
    }
  }

  // --- epilogue: normalize, bin, wave-ballot histogram ---
  int bins[4][8];
  int bmin = NBINS_ - 1, bmax = 0;
#pragma unroll
  for (int i = 0; i < 4; ++i) {
    const float fq = invq_s[rg * 4 + i];
#pragma unroll
    for (int j = 0; j < 8; ++j) {
      const int n = (j < 4) ? (cg * 4 + j) : (128 + cg * 4 + (j - 4));
      const float x = acc[i][j] * fq * invd_s[n];
      int bi = (int)floorf((x + 1.0f) * (NBINS_ * 0.5f));
      bi = bi < 0 ? 0 : (bi > NBINS_ - 1 ? NBINS_ - 1 : bi);
      bins[i][j] = bi;
      bmin = min(bmin, bi);
      bmax = max(bmax, bi);
    }
  }
#pragma unroll
  for (int m = 1; m < 64; m <<= 1) {
    bmin = min(bmin, __shfl_xor(bmin, m, 64));
    bmax = max(bmax, __shfl_xor(bmax, m, 64));
  }
  const int w = tid >> 6;       // wave id: lanes 0..31 hold q=8w+i, lanes 32..63 hold q=8w+4+i
  const int lane = tid & 63;
  unsigned int* hb = hist + (size_t)b * QL_ * NBINS_;
  for (int i = 0; i < 4; ++i) {
    const int q_lo = w * 8 + i;
    const int q_hi = w * 8 + 4 + i;
    for (int bb = bmin; bb <= bmax; ++bb) {
      unsigned int cl = 0, chi = 0;
#pragma unroll
      for (int j = 0; j < 8; ++j) {
        unsigned long long mk = __ballot(bins[i][j] == bb);
        cl += (unsigned int)__popcll(mk & 0xffffffffull);
        chi += (unsigned int)__popcll(mk >> 32);
      }
      if (lane == 0) {
        if (cl) atomicAdd(&hb[q_lo * NBINS_ + bb], cl);
        if (chi) atomicAdd(&hb[q_hi * NBINS_ + bb], chi);
      }
    }
  }
}

__global__ __launch_bounds__(64) void finalize_kernel(const unsigned int* __restrict__ hist,
                                                      const float* __restrict__ gate,
                                                      const int* __restrict__ qmask,
                                                      const float* __restrict__ W1,
                                                      const float* __restrict__ b1,
                                                      const float* __restrict__ W2,
                                                      const float* __restrict__ b2,
                                                      float* __restrict__ out) {
  const int b = blockIdx.x;
  const int l = threadIdx.x;
  float z = 0.f, e = 0.f;
  if (l < QL_) {
    const unsigned int* hc = hist + ((size_t)b * QL_ + l) * NBINS_;
    float t[5];
#pragma unroll
    for (int j = 0; j < 5; ++j) t[j] = b1[j];
    for (int i = 0; i < NBINS_; ++i) {
      const float h = log1pf((float)hc[i]);
#pragma unroll
      for (int j = 0; j < 5; ++j) t[j] = fmaf(h, W1[i * 5 + j], t[j]);
    }
    float s2 = b2[0];
#pragma unroll
    for (int j = 0; j < 5; ++j) s2 = fmaf(tanhf(t[j]), W2[j], s2);
    z = tanhf(s2);
    e = expf(gate[b * QL_ + l]) * (float)qmask[b * QL_ + l];
  }
  float esum = e;
#pragma unroll
  for (int m = 1; m < 64; m <<= 1) esum += __shfl_xor(esum, m, 64);
  const float contrib = z * (e / (esum + 1e-5f));
  float osum = contrib;
#pragma unroll
  for (int m = 1; m < 64; m <<= 1) osum += __shfl_xor(osum, m, 64);
  if (l == 0) out[b] = osum;
}

extern "C" void kernel_launch(void* const* d_in, const int* in_sizes, int n_in,
                              void* d_out, int out_size, void* d_ws, size_t ws_size,
                              hipStream_t stream) {
  const float* query = (const float*)d_in[0];
  const int* qmask = (const int*)d_in[1];
  const float* doc = (const float*)d_in[2];
  // d_in[3] = document_mask (unused by reference), d_in[4] = q_idf (unused)
  const float* W1 = (const float*)d_in[5];
  const float* b1 = (const float*)d_in[6];
  const float* W2 = (const float*)d_in[7];
  const float* b2 = (const float*)d_in[8];
  const float* Wg = (const float*)d_in[9];
  const float* bg = (const float*)d_in[10];
  float* out = (float*)d_out;

  char* ws = (char*)d_ws;
  float* invq = (float*)ws;                         // 2048 f32
  float* gate = (float*)(ws + 8192);                // 2048 f32
  unsigned int* hist = (unsigned int*)(ws + 16384); // 64*32*30 u32

  hipMemsetAsync(hist, 0, (size_t)B_ * QL_ * NBINS_ * sizeof(unsigned int), stream);

  qprep_kernel<<<dim3(B_ * QL_ / 4), dim3(256), 0, stream>>>(query, Wg, bg, invq, gate);
  interaction_kernel<<<dim3(DL_ / NT, B_), dim3(256), 0, stream>>>(query, doc, invq, hist);
  finalize_kernel<<<dim3(B_), dim3(64), 0, stream>>>(hist, gate, qmask, W1, b1, W2, b2, out);
}